// Round 3
// baseline (116.888 us; speedup 1.0000x reference)
//
#include <hip/hip_runtime.h>

// Vanilla RNN B=4096 S=512 I=1 H=16 O=1 — serial-chain latency optimization.
//
// R15: MFMA step. The R11-R14 ledger fits an issue-cadence model: wall/step
// ~= 8 cyc per DPP-class instr + 4 per plain VALU + trans deps (champion:
// 17 DPP x8 + 24 + ~30 ~= 190 cyc ✓; R14's fewer-instrs-but-more-crosslane
// = +22 ✓; chain-topology edits (R12 4x4->2x8, R13 dep-link removal) ~= 0 ✓).
// So: remove ALL cross-lane VALU from the step. One v_mfma_f32_16x16x16_f16
// computes the entire 16x16 matvec for 16 batches.
//
// Fragment alignment (the reason this works with ZERO shuffles): for
// 16x16x16_f16, C/D: col=lane&15, row=4*(lane>>4)+reg; B: col=lane&15,
// k=4*(lane>>4)+reg — SAME map. So D reg r (row 4q+r) converts lane-locally
// to B elem k=4q+r for the next step. A (weights) is loop-invariant.
// Assignment: col = batch, row/k = h-index. 16 batches/wave, 256 waves.
//
// g-trick (champion-carried): state g = 1/(2^s+1), h = 1-2g;
// s = S2LE*(rowsum(W_hh)+b_ih+b_hh) + S2LE*W_ih*x_t + (-2*S2LE*W_hh)·g.
// A = -2*S2LE*W_hh, split f16 hi+lo (2 accumulating MFMAs) so the weight
// quantization error is ~2^-22 (an f16-subnormal A_lo entry at worst
// flushes -> degrades to single-f16 weight accuracy, no corruption).
// Remaining error: per-step f16 RNE quantization of g (~2.4e-4, contracted
// by |tanh'|*||W_hh|| < 1). C-init carries x_t in f32 (exact).
//
// Loads: champion's R6 staged float4 blocks, modulo-2 named buffers; lane's
// batch row = blockIdx*16 + (lane&15) (lanes 16-63 duplicate reads; L1/L2
// absorb). Epilogue: out = (sum(W_fc)+b_fc) - 2*sum(wfc_i*g_i), in-lane
// 4-row partial then shfl_xor 16/32 (once, off the hot loop).

#define S2LE 2.8853900817779268f  // 2*log2(e)

typedef float    float4_ __attribute__((ext_vector_type(4)));
typedef _Float16 half4_  __attribute__((ext_vector_type(4)));

#if defined(__has_builtin)
#if __has_builtin(__builtin_amdgcn_mfma_f32_16x16x16f16)
#define HAVE_MFMA_BUILTIN 1
#endif
#endif

#ifdef HAVE_MFMA_BUILTIN
#define MFMA16(A, B, C) __builtin_amdgcn_mfma_f32_16x16x16f16((A), (B), (C), 0, 0, 0)
#else
static __device__ __forceinline__ float4_ mfma16_asm(half4_ a, half4_ b, float4_ c) {
    // Fallback: compiler can't see hazards through asm — generous s_nops.
    asm volatile("s_nop 1\n\t"
                 "v_mfma_f32_16x16x16_f16 %0, %1, %2, %0\n\t"
                 "s_nop 7\n\t"
                 "s_nop 7"
                 : "+v"(c) : "v"(a), "v"(b));
    return c;
}
#define MFMA16(A, B, C) mfma16_asm((A), (B), (C))
#endif

__global__ __launch_bounds__(64) void rnn_kernel(
    const float* __restrict__ x,
    const float* __restrict__ W_ih,
    const float* __restrict__ W_hh,
    const float* __restrict__ b_ih,
    const float* __restrict__ b_hh,
    const float* __restrict__ W_fc,
    const float* __restrict__ b_fc,
    float* __restrict__ out)
{
    const int l   = (int)threadIdx.x;  // 0..63
    const int col = l & 15;            // batch-in-group; A-row i; B/C/D col
    const int qr  = l >> 4;            // 0..3
    const int i4  = qr * 4;            // A k-base; C/D row-base
    const int b   = (int)(blockIdx.x * 16u + (unsigned)col);

    const float wsc = -2.0f * S2LE;

    // A-frag: A[i][k], i = col (lane&15), k = i4+r. Split f16 hi+lo.
    half4_ a_hi, a_lo;
#pragma unroll
    for (int r = 0; r < 4; ++r) {
        float u = wsc * W_hh[col * 16 + i4 + r];
        _Float16 hi = (_Float16)u;
        a_hi[r] = hi;
        a_lo[r] = (_Float16)(u - (float)hi);
    }

    // C-init constants for this lane's 4 output rows (i4+r).
    float wihS[4], biasS[4], wfcr[4];
#pragma unroll
    for (int r = 0; r < 4; ++r) {
        const int ri = i4 + r;
        float rs = 0.0f;
#pragma unroll
        for (int k = 0; k < 16; ++k) rs += W_hh[ri * 16 + k];
        wihS[r]  = W_ih[ri] * S2LE;
        biasS[r] = (rs + b_ih[ri] + b_hh[ri]) * S2LE;
        wfcr[r]  = W_fc[ri];
    }
    float cfc = b_fc[0];
#pragma unroll
    for (int k = 0; k < 16; ++k) cfc += W_fc[k];

    const float4_* __restrict__ xv = (const float4_*)(x + (size_t)b * 512);

    half4_ gB = {(_Float16)0.5f, (_Float16)0.5f, (_Float16)0.5f, (_Float16)0.5f};
    float4_ gf = {0.5f, 0.5f, 0.5f, 0.5f};  // last f32 g, for epilogue

    // One step: 4 lane-local C-init fmas (x_t in f32), 2 accumulating
    // MFMAs (lo then hi), lane-local exp2-sigmoid tail, f16 RNE repack.
#define STEP(XT) do { \
    float xt_ = (XT); \
    float4_ c; \
    c[0] = fmaf(xt_, wihS[0], biasS[0]); \
    c[1] = fmaf(xt_, wihS[1], biasS[1]); \
    c[2] = fmaf(xt_, wihS[2], biasS[2]); \
    c[3] = fmaf(xt_, wihS[3], biasS[3]); \
    c = MFMA16(a_lo, gB, c); \
    c = MFMA16(a_hi, gB, c); \
    gf[0] = __builtin_amdgcn_rcpf(__builtin_amdgcn_exp2f(c[0]) + 1.0f); \
    gf[1] = __builtin_amdgcn_rcpf(__builtin_amdgcn_exp2f(c[1]) + 1.0f); \
    gf[2] = __builtin_amdgcn_rcpf(__builtin_amdgcn_exp2f(c[2]) + 1.0f); \
    gf[3] = __builtin_amdgcn_rcpf(__builtin_amdgcn_exp2f(c[3]) + 1.0f); \
    gB[0] = (_Float16)gf[0]; \
    gB[1] = (_Float16)gf[1]; \
    gB[2] = (_Float16)gf[2]; \
    gB[3] = (_Float16)gf[3]; \
} while (0)

// 16 recurrent steps from a 4-x-float4 staged block.
#define BLOCK(BUF) do { \
    _Pragma("unroll") \
    for (int j = 0; j < 4; ++j) { \
        STEP((BUF)[j][0]); \
        STEP((BUF)[j][1]); \
        STEP((BUF)[j][2]); \
        STEP((BUF)[j][3]); \
    } \
} while (0)

    float4_ bufA[4], bufB[4];
#pragma unroll
    for (int j = 0; j < 4; ++j) bufA[j] = xv[j];  // block 0

    // Unroll-2 modulo pipeline over 32 blocks of 16 timesteps (R6): loads
    // issue one full block ahead; no register rotation, no per-iter drain.
#pragma unroll 1
    for (int i = 0; i < 32; i += 2) {
#pragma unroll
        for (int j = 0; j < 4; ++j) bufB[j] = xv[(4 * (i + 1) + j) & 127];
        BLOCK(bufA);
#pragma unroll
        for (int j = 0; j < 4; ++j) bufA[j] = xv[(4 * (i + 2) + j) & 127];
        BLOCK(bufB);
    }
#undef BLOCK
#undef STEP

    // out[b] = cfc - 2 * sum_i wfc_i * g_i  (h = 1-2g). Lane partial over
    // its 4 rows (f32 g), then cross-lane sum over the 4 qr groups.
    float p = gf[0] * wfcr[0] + gf[1] * wfcr[1] + gf[2] * wfcr[2] + gf[3] * wfcr[3];
    p += __shfl_xor(p, 16, 64);
    p += __shfl_xor(p, 32, 64);
    if (qr == 0) out[b] = fmaf(-2.0f, p, cfc);
}

extern "C" void kernel_launch(void* const* d_in, const int* in_sizes, int n_in,
                              void* d_out, int out_size, void* d_ws, size_t ws_size,
                              hipStream_t stream) {
    const float* x    = (const float*)d_in[0];
    const float* W_ih = (const float*)d_in[1];
    const float* W_hh = (const float*)d_in[2];
    const float* b_ih = (const float*)d_in[3];
    const float* b_hh = (const float*)d_in[4];
    const float* W_fc = (const float*)d_in[5];
    const float* b_fc = (const float*)d_in[6];
    float* out = (float*)d_out;

    rnn_kernel<<<256, 64, 0, stream>>>(x, W_ih, W_hh, b_ih, b_hh, W_fc, b_fc, out);
}